// Round 11
// baseline (1282.916 us; speedup 1.0000x reference)
//
#include <hip/hip_runtime.h>
#include <hip/hip_bf16.h>

// Problem constants (B, C, H, W) = (8, 1024, 64, 64); N = H*W = 4096.
#define BATCH 8
#define CH    1024
#define NN    4096

typedef __attribute__((ext_vector_type(8))) short bf16x8;   // 8 bf16 = 4 VGPRs
typedef __attribute__((ext_vector_type(4))) float f32x4;
using bf16 = __hip_bfloat16;

struct bhalf4 { bf16 x, y, z, w; };               // 8 bytes

__device__ __forceinline__ unsigned short f2bfu(float f) {
  bf16 h = __float2bfloat16(f);
  return *reinterpret_cast<unsigned short*>(&h);
}

// ---------------------------------------------------------------------------
// Transpose + cast + asq: prev_key [B][C][N] fp32 -> mk_t [B][N][C] bf16
// (row-major; GEMM1's B operand, staged via DMA). Proven r5-r10 kernel.
// ---------------------------------------------------------------------------
__global__ __launch_bounds__(256) void transpose_cast_asq(
    const float* __restrict__ in_all, bf16* __restrict__ out_all,
    float* __restrict__ asq_all) {
  int bz = blockIdx.z;
  const float* in = in_all + (size_t)bz * CH * NN;
  bf16* out = out_all + (size_t)bz * NN * CH;

  __shared__ float tile[64][65];
  __shared__ float sqb[16][64];

  int n0 = blockIdx.x * 64;
  int c0 = blockIdx.y * 64;
  int t = threadIdx.x;
  int nc = t & 15;
  int cr = t >> 4;

  float4 sq4 = make_float4(0.f, 0.f, 0.f, 0.f);
#pragma unroll
  for (int i = 0; i < 4; ++i) {
    int c = cr + i * 16;
    float4 v = *(const float4*)(in + (size_t)(c0 + c) * NN + n0 + nc * 4);
    tile[c][nc * 4 + 0] = v.x;
    tile[c][nc * 4 + 1] = v.y;
    tile[c][nc * 4 + 2] = v.z;
    tile[c][nc * 4 + 3] = v.w;
    sq4.x += v.x * v.x; sq4.y += v.y * v.y;
    sq4.z += v.z * v.z; sq4.w += v.w * v.w;
  }
  sqb[cr][nc * 4 + 0] = sq4.x;
  sqb[cr][nc * 4 + 1] = sq4.y;
  sqb[cr][nc * 4 + 2] = sq4.z;
  sqb[cr][nc * 4 + 3] = sq4.w;
  __syncthreads();
  if (t < 64) {
    float s = 0.f;
#pragma unroll
    for (int i = 0; i < 16; ++i) s += sqb[i][t];
    atomicAdd(&asq_all[(size_t)bz * NN + n0 + t], s);
  }
  int cchunk = t & 7;
  int nb = t >> 3;
#pragma unroll
  for (int p = 0; p < 2; ++p) {
    int n = nb + p * 32;
    bf16x8 o;
#pragma unroll
    for (int j = 0; j < 8; ++j)
      o[j] = (short)f2bfu(tile[cchunk * 8 + j][n]);
    *(bf16x8*)(out + (size_t)(n0 + n) * CH + c0 + cchunk * 8) = o;
  }
}

// ---------------------------------------------------------------------------
// Transpose + PACK: curr_key [B][C][N] fp32 -> qk_p packed-fragment bf16.
// Packed layout: 16x32 subtile (rb over n-rows, kb over k=c, NKB=CH/32):
//   lane l holds A[rb*16 + (l&15)][kb*32 + (l>>4)*8 + j], j=0..7 (16B),
//   stored at ((rb*NKB + kb)*64 + l)*8 elems -> 1 KB contiguous per subtile.
// GEMM reads one subtile per wave per b128 load, perfectly coalesced.
// ---------------------------------------------------------------------------
__global__ __launch_bounds__(256) void transpose_pack(
    const float* __restrict__ in_all, bf16* __restrict__ out_all) {
  int bz = blockIdx.z;
  const float* in = in_all + (size_t)bz * CH * NN;
  bf16* out = out_all + (size_t)bz * NN * CH;   // packed region, same size

  __shared__ float tile[64][65];
  int n0 = blockIdx.x * 64;
  int c0 = blockIdx.y * 64;
  int t = threadIdx.x;
  int nc = t & 15;
  int cr = t >> 4;
#pragma unroll
  for (int i = 0; i < 4; ++i) {
    int c = cr + i * 16;
    float4 v = *(const float4*)(in + (size_t)(c0 + c) * NN + n0 + nc * 4);
    tile[c][nc * 4 + 0] = v.x;
    tile[c][nc * 4 + 1] = v.y;
    tile[c][nc * 4 + 2] = v.z;
    tile[c][nc * 4 + 3] = v.w;
  }
  __syncthreads();
  // 8 subtiles in this 64x64 region: s = rbl(2b) | kbl<<2; 512 (s,l) slots.
  constexpr int NKB = CH / 32;   // 32
#pragma unroll
  for (int p = 0; p < 2; ++p) {
    int q = p * 256 + t;
    int s = q >> 6, l = q & 63;
    int rbl = s & 3, kbl = s >> 2;
    int cl = kbl * 32 + (l >> 4) * 8;
    int nl = rbl * 16 + (l & 15);
    bf16x8 o;
#pragma unroll
    for (int j = 0; j < 8; ++j) o[j] = (short)f2bfu(tile[cl + j][nl]);
    size_t rb = (size_t)(n0 >> 4) + rbl;
    size_t kb = (size_t)(c0 >> 5) + kbl;
    *(bf16x8*)(out + (rb * NKB + kb) * 512 + l * 8) = o;
  }
}

// ---------------------------------------------------------------------------
// Convert + PACK: prev_value [B][C][N] fp32 -> mo_p packed-fragment bf16.
// rb over c (CH/16), kb over m=n (NKB=NN/32). Block: 16 c-rows x 128 m.
// ---------------------------------------------------------------------------
__global__ __launch_bounds__(256) void convert_pack(
    const float* __restrict__ in_all, bf16* __restrict__ out_all) {
  int bz = blockIdx.z;
  const float* in = in_all + (size_t)bz * CH * NN;
  bf16* out = out_all + (size_t)bz * CH * NN;

  __shared__ float tile[16][132];     // +4 pad: conflict-free packed reads
  int m0 = blockIdx.x * 128;
  int c0 = blockIdx.y * 16;
  int t = threadIdx.x;
  int mq = t & 31;        // float4 col (32 per row)
  int cr = t >> 5;        // 0..7
#pragma unroll
  for (int i = 0; i < 2; ++i) {
    int c = cr + i * 8;
    float4 v = *(const float4*)(in + (size_t)(c0 + c) * NN + m0 + mq * 4);
    tile[c][mq * 4 + 0] = v.x;
    tile[c][mq * 4 + 1] = v.y;
    tile[c][mq * 4 + 2] = v.z;
    tile[c][mq * 4 + 3] = v.w;
  }
  __syncthreads();
  constexpr int NKB = NN / 32;   // 128
  int s = t >> 6, l = t & 63;    // 4 subtiles x 64 lanes
  int cl = l & 15;
  int ml = s * 32 + (l >> 4) * 8;
  bf16x8 o;
#pragma unroll
  for (int j = 0; j < 8; ++j) o[j] = (short)f2bfu(tile[cl][ml + j]);
  size_t rb = (size_t)(c0 >> 4);
  size_t kb = (size_t)(m0 >> 5) + s;
  *(bf16x8*)(out + (rb * NKB + kb) * 512 + l * 8) = o;
}

// ---------------------------------------------------------------------------
// Copy curr_value into the second half of each batch's output channel block.
// ---------------------------------------------------------------------------
__global__ __launch_bounds__(256) void copy_curr(
    const float4* __restrict__ src, float4* __restrict__ dst) {
  size_t idx = (size_t)blockIdx.x * 256 + threadIdx.x;
  size_t b = idx >> 20;
  size_t r = idx & 1048575;
  dst[b * 2097152 + 1048576 + r] = src[idx];
}

// ---------------------------------------------------------------------------
// A-DIRECT GEMM (round 11): block 512x64, 4 waves stacked vertically
// (wave w owns rows by*512 + w*128 .. +128, all 64 cols). A-fragments are
// wave-private -> streamed global->registers from the packed layout
// (1 KB coalesced loads, zero LDS); only the shared 64-row B-panel goes
// through LDS (3 x 4 KB buffers). LDS traffic/tile/CU: 144 KB -> 40 KB.
//
// Per tile t (ONE barrier):
//   ds_read bF (4 x b128, buf cb); load A(t+1)->regs (8 x b128 global);
//   stage B(t+2)->buf sb (1 gload_lds/thread); lgkm0+schedbar;
//   MFMA x32 (A(t) regs, bF); vmcnt(1) [tails 0]; BARR.
// vmcnt queue trace (steady): enter [B(t+1)]; issue A(t+1)x8, B(t+2);
// vmcnt(1) drains B(t+1) (next tile's ds_read) + A(t+1) (next MFMA),
// leaves B(t+2) in flight. Tails drain to 0.
// Stage-vs-read race: buf sb's readers were tile t-1's bF reads, drained
// at t-1's lgkm0 before t-1's barrier -> stage at t is 1 barrier later. SAFE.
// Pair-unrolled with NAMED register sets a0/a1 (rule 20).
//
// MODE 0 (gemm1): e = exp((2*acc - asq[n])/32) -> P bf16 + rowsum atomics.
// MODE 1 (gemm2): acc / rowsum[n] -> fp32 out.  TM = M/512.
// ---------------------------------------------------------------------------
#define BARR() __builtin_amdgcn_s_barrier()
#define PRIO(x) __builtin_amdgcn_s_setprio(x)
#define LDS_FENCE() do {                                      \
    asm volatile("s_waitcnt lgkmcnt(0)" ::: "memory");        \
    __builtin_amdgcn_sched_barrier(0);                        \
  } while (0)
#define MEM_FENCE() do {                                      \
    asm volatile("" ::: "memory");                            \
    __builtin_amdgcn_sched_barrier(0);                        \
  } while (0)

template <int K, int MODE, int TM>
__global__ __launch_bounds__(256, 2) void gemm_ad(
    const bf16* __restrict__ Apk, const bf16* __restrict__ Ball,
    bf16* __restrict__ Pall, float* __restrict__ Oall,
    const float* __restrict__ asq_all, float* __restrict__ rsum_all) {
  constexpr int NT = K / 32;           // even for all instantiations
  constexpr int NKB = K / 32;
  constexpr int TN = NN / 64;          // 64
  constexpr int NWG = TM * TN * BATCH;
  constexpr int GRP = (TM < 8) ? TM : 8;

  // XCD-bijective swizzle (NWG % 8 == 0) + L2 grouping (bx-major over
  // by-groups of GRP -> B-panel reused GRP x back-to-back).
  int lid = blockIdx.x;
  int swz = (lid & 7) * (NWG >> 3) + (lid >> 3);
  int bz  = swz / (TM * TN);
  int rem = swz - bz * (TM * TN);
  int g  = rem / (GRP * TN);
  int r2 = rem - g * (GRP * TN);
  int bx = r2 / GRP;
  int by = g * GRP + (r2 & (GRP - 1));

  const bf16* Bb = Ball + (size_t)bz * NN * (size_t)K + (size_t)(bx * 64) * K;

  __shared__ bf16 Bs[8192];            // 16 KB: 3 x 4KB bufs + epi scratch

  int tid = threadIdx.x;
  int wv = tid >> 6, lane = tid & 63;
  int fl = lane & 15, quad = lane >> 4;

  // B staging: 64 rows x 32 k = 4 KB/tile, 1 x 16B per thread.
  // row = tid>>2, global chunk = (tid&3) ^ ((row>>1)&3) (inverse of read swz).
  int rS = tid >> 2;
  int cS = (tid & 3) ^ ((rS >> 1) & 3);
  const bf16* gB = Bb + (size_t)rS * K + cS * 8;
  int lsB = wv * 512;                  // wave-uniform LDS elem offset

  // B fragment reads (swizzle chunk ^= (row>>1)&3; lane-constant).
  int kq = (quad ^ ((fl >> 1) & 3)) * 8;
  int boff = fl * 32 + kq;             // + nj*512

  // A packed stream base (lane offset folded in); advance 512 elems/tile.
  int rb0 = by * 32 + wv * 8;          // (by*512 + wv*128)/16
  const bf16* aB = Apk + (size_t)bz * ((size_t)TM * 512) * K +
                   (size_t)rb0 * NKB * 512 + lane * 8;

  f32x4 acc[8][4] = {};
  bf16x8 a0[8], a1[8], bF[4];

#define LOADA(DST) do {                                                       \
    _Pragma("unroll")                                                         \
    for (int mi_ = 0; mi_ < 8; ++mi_)                                         \
      DST[mi_] = *(const bf16x8*)(aB + (size_t)mi_ * (NKB * 512));            \
    aB += 512;                                                                \
  } while (0)
#define STAGEB(SB) do {                                                       \
    __builtin_amdgcn_global_load_lds(                                         \
        (const __attribute__((address_space(1))) void*)gB,                    \
        (__attribute__((address_space(3))) void*)(Bs + (SB) * 2048 + lsB),    \
        16, 0, 0);                                                            \
    gB += 32;                                                                 \
  } while (0)
#define RDB(CB) do {                                                          \
    _Pragma("unroll")                                                         \
    for (int nj_ = 0; nj_ < 4; ++nj_)                                         \
      bF[nj_] = *(const bf16x8*)(Bs + (CB) * 2048 + boff + nj_ * 512);        \
  } while (0)
#define MFMA8(AS) do {                                                        \
    PRIO(1);                                                                  \
    _Pragma("unroll")                                                         \
    for (int mi_ = 0; mi_ < 8; ++mi_)                                         \
      _Pragma("unroll")                                                       \
      for (int nj_ = 0; nj_ < 4; ++nj_)                                       \
        acc[mi_][nj_] = __builtin_amdgcn_mfma_f32_16x16x32_bf16(              \
            AS[mi_], bF[nj_], acc[mi_][nj_], 0, 0, 0);                        \
    PRIO(0);                                                                  \
  } while (0)

  // Prologue: stage B0 -> buf0, B1 -> buf1; load A(0); drain all; barrier.
  STAGEB(0);
  STAGEB(1);
  LOADA(a0);
  asm volatile("s_waitcnt vmcnt(0)" ::: "memory");
  BARR();

  int cb = 0, sb = 2;
  for (int t = 0; t < NT; t += 2) {
    // ---- even tile t: consume a0; load A(t+1)->a1; stage B(t+2) ----
    RDB(cb);
    LOADA(a1);                         // t+1 <= NT-1 (NT even)
    if (t + 2 < NT) STAGEB(sb);
    asm volatile("s_waitcnt lgkmcnt(0)" ::: "memory");
    __builtin_amdgcn_sched_barrier(0);
    MFMA8(a0);
    if (t + 2 < NT) { asm volatile("s_waitcnt vmcnt(1)" ::: "memory"); }
    else            { asm volatile("s_waitcnt vmcnt(0)" ::: "memory"); }
    BARR();
    cb = (cb == 2) ? 0 : cb + 1;
    sb = (sb == 2) ? 0 : sb + 1;

    // ---- odd tile t+1: consume a1; load A(t+2)->a0; stage B(t+3) ----
    RDB(cb);
    if (t + 2 < NT) LOADA(a0);
    if (t + 3 < NT) STAGEB(sb);
    asm volatile("s_waitcnt lgkmcnt(0)" ::: "memory");
    __builtin_amdgcn_sched_barrier(0);
    MFMA8(a1);
    if (t + 3 < NT) { asm volatile("s_waitcnt vmcnt(1)" ::: "memory"); }
    else            { asm volatile("s_waitcnt vmcnt(0)" ::: "memory"); }
    BARR();
    cb = (cb == 2) ? 0 : cb + 1;
    sb = (sb == 2) ? 0 : sb + 1;
  }
#undef LOADA
#undef STAGEB
#undef RDB
#undef MFMA8

  // All loads drained (tail vmcnt(0)); sync before LDS scratch reuse.
  __syncthreads();

  // ---- Epilogue: wave-private 16x64 LDS transpose -> 16B stores ----
  int colbase = bx * 64;
  int rowg0 = by * 512 + wv * 128;

  if constexpr (MODE == 0) {
    const float* asq = asq_all + (size_t)bz * NN;
    float* rsum = rsum_all + (size_t)bz * NN;
    bf16* P = Pall + (size_t)bz * NN * NN;
    short* scr = (short*)Bs + wv * 1024;   // 16x64 bf16 per wave (8 KB tot)

    float aq[4];
#pragma unroll
    for (int nj = 0; nj < 4; ++nj) aq[nj] = asq[colbase + nj * 16 + fl];

    float rs[8][4];
#pragma unroll
    for (int mi = 0; mi < 8; ++mi)
#pragma unroll
      for (int r = 0; r < 4; ++r) rs[mi][r] = 0.f;

#pragma unroll
    for (int mi = 0; mi < 8; ++mi) {
#pragma unroll
      for (int nj = 0; nj < 4; ++nj)
#pragma unroll
        for (int r = 0; r < 4; ++r) {
          int row = (quad << 2) + r;
          float e = __expf((2.f * acc[mi][nj][r] - aq[nj]) * 0.03125f);
          rs[mi][r] += e;
          int chunk = (nj * 2 + (fl >> 3)) ^ (row & 7);
          scr[row * 64 + chunk * 8 + (fl & 7)] = (short)f2bfu(e);
        }
      LDS_FENCE();
#pragma unroll
      for (int p = 0; p < 2; ++p) {
        int row = (p << 3) + (lane >> 3);
        int c = lane & 7;
        int chunk = c ^ (row & 7);
        bf16x8 v = *(const bf16x8*)(scr + row * 64 + chunk * 8);
        *(bf16x8*)(P + (size_t)(rowg0 + mi * 16 + row) * NN + colbase + c * 8) = v;
      }
      MEM_FENCE();
    }
#pragma unroll
    for (int mi = 0; mi < 8; ++mi)
#pragma unroll
      for (int r = 0; r < 4; ++r) {
        float v = rs[mi][r];
        v += __shfl_xor(v, 1);
        v += __shfl_xor(v, 2);
        v += __shfl_xor(v, 4);
        v += __shfl_xor(v, 8);
        if (fl == 0)
          atomicAdd(&rsum[rowg0 + mi * 16 + (quad << 2) + r], v);
      }
  } else {
    float* Co = Oall + (size_t)bz * 2 * CH * NN;     // first CV block
    const float* rsum = rsum_all + (size_t)bz * NN;
    float* scr = (float*)Bs + wv * 1024;             // 16x64 f32 (16 KB tot)

    float inv[4];
#pragma unroll
    for (int nj = 0; nj < 4; ++nj) inv[nj] = 1.f / rsum[colbase + nj * 16 + fl];

#pragma unroll
    for (int mi = 0; mi < 8; ++mi) {
#pragma unroll
      for (int nj = 0; nj < 4; ++nj)
#pragma unroll
        for (int r = 0; r < 4; ++r) {
          int row = (quad << 2) + r;
          int chunk = (nj * 4 + (fl >> 2)) ^ (row & 15);
          scr[row * 64 + chunk * 4 + (fl & 3)] = acc[mi][nj][r] * inv[nj];
        }
      LDS_FENCE();
#pragma unroll
      for (int p = 0; p < 4; ++p) {
        int row = (p << 2) + (lane >> 4);
        int c = lane & 15;
        int chunk = c ^ (row & 15);
        f32x4 v = *(const f32x4*)(scr + row * 64 + chunk * 4);
        *(f32x4*)(Co + (size_t)(rowg0 + mi * 16 + row) * NN + colbase + c * 4) = v;
      }
      MEM_FENCE();
    }
  }
}

// ---------------------------------------------------------------------------
extern "C" void kernel_launch(void* const* d_in, const int* in_sizes, int n_in,
                              void* d_out, int out_size, void* d_ws, size_t ws_size,
                              hipStream_t stream) {
  const float* prev_key   = (const float*)d_in[0];
  const float* prev_value = (const float*)d_in[1];
  const float* curr_key   = (const float*)d_in[2];
  const float* curr_value = (const float*)d_in[3];
  float* out = (float*)d_out;

  char* ws = (char*)d_ws;
  bf16* P     = (bf16*)(ws);                        // 256 MB [B][N][N]
  bf16* mk_t  = (bf16*)(ws + 268435456u);           //  64 MB [B][N][C] row-major
  bf16* qk_p  = (bf16*)(ws + 335544320u);           //  64 MB packed frags
  bf16* mo_p  = (bf16*)(ws + 402653184u);           //  64 MB packed frags
  float* a_sq = (float*)(ws + 469762048u);          // 128 KB [B][N]
  float* rsum = a_sq + (size_t)BATCH * NN;          // 128 KB [B][N]

  hipMemsetAsync(a_sq, 0, 2ull * BATCH * NN * sizeof(float), stream);

  transpose_cast_asq<<<dim3(NN / 64, CH / 64, BATCH), 256, 0, stream>>>(
      prev_key, mk_t, a_sq);
  transpose_pack<<<dim3(NN / 64, CH / 64, BATCH), 256, 0, stream>>>(
      curr_key, qk_p);
  convert_pack<<<dim3(NN / 128, CH / 16, BATCH), 256, 0, stream>>>(
      prev_value, mo_p);
  copy_curr<<<(size_t)BATCH * CH * NN / 4 / 256, 256, 0, stream>>>(
      (const float4*)curr_value, (float4*)out);

  // GEMM1: ab = qk * mk^T (M=N=4096, K=1024), A=qk packed, B=mk row-major.
  gemm_ad<CH, 0, 8><<<dim3(8 * 64 * BATCH), dim3(256), 0, stream>>>(
      qk_p, mk_t, P, nullptr, a_sq, rsum);

  // GEMM2: mem = mo * P^T (M=1024, N=4096, K=4096), A=mo packed, B=P.
  gemm_ad<NN, 1, 2><<<dim3(2 * 64 * BATCH), dim3(256), 0, stream>>>(
      mo_p, P, nullptr, out, nullptr, rsum);
}

// Round 12
// 1216.093 us; speedup vs baseline: 1.0549x; 1.0549x over previous
//
#include <hip/hip_runtime.h>
#include <hip/hip_bf16.h>

// Problem constants (B, C, H, W) = (8, 1024, 64, 64); N = H*W = 4096.
#define BATCH 8
#define CH    1024
#define NN    4096

typedef __attribute__((ext_vector_type(8))) short bf16x8;   // 8 bf16 = 4 VGPRs
typedef __attribute__((ext_vector_type(4))) float f32x4;
using bf16 = __hip_bfloat16;

struct bhalf4 { bf16 x, y, z, w; };               // 8 bytes

__device__ __forceinline__ unsigned short f2bfu(float f) {
  bf16 h = __float2bfloat16(f);
  return *reinterpret_cast<unsigned short*>(&h);
}

// ---------------------------------------------------------------------------
// Vectorized transpose + cast: in [B][C][N] fp32 -> out [B][N][C] bf16.
// (proven r5-r10 kernel, unchanged)
// ---------------------------------------------------------------------------
template <bool ASQ>
__global__ __launch_bounds__(256) void transpose_cast_v(
    const float* __restrict__ in_all, bf16* __restrict__ out_all,
    float* __restrict__ asq_all) {
  int bz = blockIdx.z;
  const float* in = in_all + (size_t)bz * CH * NN;
  bf16* out = out_all + (size_t)bz * NN * CH;

  __shared__ float tile[64][65];
  __shared__ float sqb[16][64];

  int n0 = blockIdx.x * 64;
  int c0 = blockIdx.y * 64;
  int t = threadIdx.x;
  int nc = t & 15;
  int cr = t >> 4;

  float4 sq4 = make_float4(0.f, 0.f, 0.f, 0.f);
#pragma unroll
  for (int i = 0; i < 4; ++i) {
    int c = cr + i * 16;
    float4 v = *(const float4*)(in + (size_t)(c0 + c) * NN + n0 + nc * 4);
    tile[c][nc * 4 + 0] = v.x;
    tile[c][nc * 4 + 1] = v.y;
    tile[c][nc * 4 + 2] = v.z;
    tile[c][nc * 4 + 3] = v.w;
    if (ASQ) {
      sq4.x += v.x * v.x; sq4.y += v.y * v.y;
      sq4.z += v.z * v.z; sq4.w += v.w * v.w;
    }
  }
  if (ASQ) {
    sqb[cr][nc * 4 + 0] = sq4.x;
    sqb[cr][nc * 4 + 1] = sq4.y;
    sqb[cr][nc * 4 + 2] = sq4.z;
    sqb[cr][nc * 4 + 3] = sq4.w;
  }
  __syncthreads();
  if (ASQ && t < 64) {
    float s = 0.f;
#pragma unroll
    for (int i = 0; i < 16; ++i) s += sqb[i][t];
    atomicAdd(&asq_all[(size_t)bz * NN + n0 + t], s);
  }
  int cchunk = t & 7;
  int nb = t >> 3;
#pragma unroll
  for (int p = 0; p < 2; ++p) {
    int n = nb + p * 32;
    bf16x8 o;
#pragma unroll
    for (int j = 0; j < 8; ++j)
      o[j] = (short)f2bfu(tile[cchunk * 8 + j][n]);
    *(bf16x8*)(out + (size_t)(n0 + n) * CH + c0 + cchunk * 8) = o;
  }
}

// ---------------------------------------------------------------------------
// 256x128 block / 128x64 per-wave / BK=32 / 3-buffer GEMM (C = A * B^T).
// EXACT round-8 loop + epilogue (best passing structure: R7 read-ahead, R9
// split-phase, R11 A-direct all regressed -> this is the keeper).
//
// ROUND-12 ADDITION (FUSE=true, GEMM1 only): every 5th block (bid%5==4) is
// a MEMORY-TASK block instead of a GEMM tile -- 512 blocks stream-convert
// prev_value fp32->bf16 (mo_b, consumed only by GEMM2, next launch) and 512
// blocks copy curr_value into out's second channel half (disjoint from all
// GEMM1/GEMM2 accesses). These 440 MB of independent streaming hide under
// GEMM1's spare HBM bandwidth instead of running serially. Exact mapping:
// grid = 5120 = 5*1024; mem idx = bid/5; gemm lid = bid - bid/5 covers
// 0..4095 bijectively (bid = 5k+r, r<4 -> lid = 4k+r).
//
// Per tile t: {12 ds_read(t); stage(t+2)->buf[(t+2)%3]; BARR; lgkmcnt(0);
//              sched_barrier; 32 MFMA; vmcnt(6) [tail 0]; BARR}
// Race audit (rounds 6/8): stage targets buf[(t+2)%3] whose prior readers
// (tile t-1) drained at their lgkm0 >= 1 barrier earlier; vmcnt(6) leaves
// exactly t+2's 6 loads in flight so t+1's data landed before its reads.
// ---------------------------------------------------------------------------
#define BARR() __builtin_amdgcn_s_barrier()
#define PRIO(x) __builtin_amdgcn_s_setprio(x)
#define LDS_FENCE() do {                                      \
    asm volatile("s_waitcnt lgkmcnt(0)" ::: "memory");        \
    __builtin_amdgcn_sched_barrier(0);                        \
  } while (0)
#define MEM_FENCE() do {                                      \
    asm volatile("" ::: "memory");                            \
    __builtin_amdgcn_sched_barrier(0);                        \
  } while (0)

__device__ __forceinline__ void gload16(const bf16* g, bf16* l) {
  __builtin_amdgcn_global_load_lds(
      (const __attribute__((address_space(1))) void*)g,
      (__attribute__((address_space(3))) void*)l, 16, 0, 0);
}

template <int K, int MODE, int TM, int TN, bool FUSE>
__global__ __launch_bounds__(256, 2) void gemm_s3(
    const bf16* __restrict__ Aall, const bf16* __restrict__ Ball,
    bf16* __restrict__ Pall, float* __restrict__ Oall,
    const float* __restrict__ asq_all, float* __restrict__ rsum_all,
    const float4* __restrict__ pv_src, bhalf4* __restrict__ mo_dst,
    const float4* __restrict__ cv_src, float4* __restrict__ out_dst) {
  constexpr int NT = K / 32;
  constexpr int TPB = TM * TN;
  constexpr int NWG = TPB * BATCH;
  constexpr int GRP = (TM < 8) ? TM : 8;

  int lid;
  if constexpr (FUSE) {
    int bid = blockIdx.x;
    if ((bid % 5) == 4) {
      // ---- memory-task block: convert (mb<512) or copy (mb>=512) ----
      int mb = bid / 5;                       // 0..1023
      int tid = threadIdx.x;
      if (mb < 512) {
        size_t idx = (size_t)mb * 256 + tid;  // stride 131072, 64 iters
#pragma unroll 4
        for (int i = 0; i < 64; ++i, idx += 131072) {
          float4 v = pv_src[idx];
          bhalf4 o;
          o.x = __float2bfloat16(v.x);
          o.y = __float2bfloat16(v.y);
          o.z = __float2bfloat16(v.z);
          o.w = __float2bfloat16(v.w);
          mo_dst[idx] = o;
        }
      } else {
        size_t idx = (size_t)(mb - 512) * 256 + tid;
#pragma unroll 4
        for (int i = 0; i < 64; ++i, idx += 131072) {
          float4 v = cv_src[idx];
          size_t b = idx >> 20;
          size_t r = idx & 1048575;
          out_dst[b * 2097152 + 1048576 + r] = v;
        }
      }
      return;
    }
    lid = bid - bid / 5;                      // bijective onto 0..NWG-1
  } else {
    lid = blockIdx.x;
  }

  // XCD-bijective swizzle (NWG % 8 == 0) + L2 grouping.
  int swz = (lid & 7) * (NWG >> 3) + (lid >> 3);
  int bz  = swz / TPB;
  int rem = swz - bz * TPB;
  int g  = rem / (GRP * TN);
  int r2 = rem - g * (GRP * TN);
  int bx = r2 / GRP;
  int by = g * GRP + (r2 & (GRP - 1));

  const bf16* Ab = Aall + (size_t)bz * TM * 256 * K + (size_t)(by * 256) * K;
  const bf16* Bb = Ball + (size_t)bz * TN * 128 * K + (size_t)(bx * 128) * K;

  __shared__ bf16 As[3][256 * 32];     // 48 KiB
  __shared__ bf16 Bs[3][128 * 32];     // 24 KiB
  bf16* const AsB = &As[0][0];
  bf16* const BsB = &Bs[0][0];

  int tid = threadIdx.x;
  int wv = tid >> 6, lane = tid & 63;
  int fl = lane & 15, quad = lane >> 4;
  int wr = wv >> 1, wc = wv & 1;       // 2x2 waves; wave tile 128x64

  // Staging addresses (pre-swizzled global source; linear LDS dest).
  int rA0 = tid >> 2,           cA0 = (tid & 3) ^ ((rA0 >> 1) & 3);
  int rA1 = (256 + tid) >> 2,   cA1 = ((256 + tid) & 3) ^ ((rA1 >> 1) & 3);
  int rA2 = (512 + tid) >> 2,   cA2 = ((512 + tid) & 3) ^ ((rA2 >> 1) & 3);
  int rA3 = (768 + tid) >> 2,   cA3 = ((768 + tid) & 3) ^ ((rA3 >> 1) & 3);
  const bf16* gA0 = Ab + (size_t)rA0 * K + cA0 * 8;
  const bf16* gA1 = Ab + (size_t)rA1 * K + cA1 * 8;
  const bf16* gA2 = Ab + (size_t)rA2 * K + cA2 * 8;
  const bf16* gA3 = Ab + (size_t)rA3 * K + cA3 * 8;
  const bf16* gB0 = Bb + (size_t)rA0 * K + cA0 * 8;   // B rows 0..63
  const bf16* gB1 = Bb + (size_t)rA1 * K + cA1 * 8;   // B rows 64..127
  int lsu = wv * 512;                  // wave-uniform lane-block offset

  // Fragment-read offsets (swizzle chunk ^= (row>>1)&3; lane-constant).
  int kq = (quad ^ ((fl >> 1) & 3)) * 8;
  int aoff = (wr * 128 + fl) * 32 + kq;
  int boff = (wc * 64 + fl) * 32 + kq;

  f32x4 acc[8][4] = {};

#define STAGE2(SB) do {                                                       \
    bf16* da = AsB + (SB) * 8192;                                             \
    bf16* db = BsB + (SB) * 4096;                                             \
    gload16(gA0, da + lsu);        gload16(gA1, da + 2048 + lsu);             \
    gload16(gA2, da + 4096 + lsu); gload16(gA3, da + 6144 + lsu);             \
    gload16(gB0, db + lsu);        gload16(gB1, db + 2048 + lsu);             \
    gA0 += 32; gA1 += 32; gA2 += 32; gA3 += 32; gB0 += 32; gB1 += 32;         \
  } while (0)

  // Prologue: stage tile 0 -> buf0, tile 1 -> buf1; drain tile 0 only.
  STAGE2(0);
  STAGE2(1);
  asm volatile("s_waitcnt vmcnt(6)" ::: "memory");
  BARR();

  int cb = 0, sb = 2;
  for (int t = 0; t < NT; ++t) {
    const bf16* Ac = AsB + cb * 8192;
    const bf16* Bc = BsB + cb * 4096;
    bf16x8 aF[8], bF[4];
#pragma unroll
    for (int mi = 0; mi < 8; ++mi)
      aF[mi] = *(const bf16x8*)(Ac + aoff + mi * 512);
#pragma unroll
    for (int nj = 0; nj < 4; ++nj)
      bF[nj] = *(const bf16x8*)(Bc + boff + nj * 512);

    if (t + 2 < NT) STAGE2(sb);

    BARR();
    asm volatile("s_waitcnt lgkmcnt(0)" ::: "memory");
    __builtin_amdgcn_sched_barrier(0);
    PRIO(1);
#pragma unroll
    for (int mi = 0; mi < 8; ++mi)
#pragma unroll
      for (int nj = 0; nj < 4; ++nj)
        acc[mi][nj] = __builtin_amdgcn_mfma_f32_16x16x32_bf16(
            aF[mi], bF[nj], acc[mi][nj], 0, 0, 0);
    PRIO(0);
    if (t + 2 < NT) {
      asm volatile("s_waitcnt vmcnt(6)" ::: "memory");
    } else {
      asm volatile("s_waitcnt vmcnt(0)" ::: "memory");
    }
    BARR();

    cb = (cb == 2) ? 0 : cb + 1;
    sb = (sb == 2) ? 0 : sb + 1;
  }
#undef STAGE2

  // All staging drained (tail vmcnt(0)) and reads consumed; sync before
  // reusing LDS as epilogue scratch.
  __syncthreads();

  // ---- Epilogue: wave-private 16x64 LDS transpose -> 16B stores ----
  int colbase = bx * 128 + wc * 64;
  int rowg0 = by * 256 + wr * 128;

  if constexpr (MODE == 0) {
    const float* asq = asq_all + (size_t)bz * NN;
    float* rsum = rsum_all + (size_t)bz * NN;
    bf16* P = Pall + (size_t)bz * NN * NN;
    short* scr = (short*)AsB + wv * 1024;   // 16x64 bf16 per wave

    float aq[4];
#pragma unroll
    for (int nj = 0; nj < 4; ++nj) aq[nj] = asq[colbase + nj * 16 + fl];

    float rs[8][4];
#pragma unroll
    for (int mi = 0; mi < 8; ++mi)
#pragma unroll
      for (int r = 0; r < 4; ++r) rs[mi][r] = 0.f;

#pragma unroll
    for (int mi = 0; mi < 8; ++mi) {
#pragma unroll
      for (int nj = 0; nj < 4; ++nj)
#pragma unroll
        for (int r = 0; r < 4; ++r) {
          int row = (quad << 2) + r;
          float e = __expf((2.f * acc[mi][nj][r] - aq[nj]) * 0.03125f);
          rs[mi][r] += e;
          int chunk = (nj * 2 + (fl >> 3)) ^ (row & 7);
          scr[row * 64 + chunk * 8 + (fl & 7)] = (short)f2bfu(e);
        }
      LDS_FENCE();
#pragma unroll
      for (int p = 0; p < 2; ++p) {
        int row = (p << 3) + (lane >> 3);
        int c = lane & 7;
        int chunk = c ^ (row & 7);
        bf16x8 v = *(const bf16x8*)(scr + row * 64 + chunk * 8);
        *(bf16x8*)(P + (size_t)(rowg0 + mi * 16 + row) * NN + colbase + c * 8) = v;
      }
      MEM_FENCE();
    }
#pragma unroll
    for (int mi = 0; mi < 8; ++mi)
#pragma unroll
      for (int r = 0; r < 4; ++r) {
        float v = rs[mi][r];
        v += __shfl_xor(v, 1);
        v += __shfl_xor(v, 2);
        v += __shfl_xor(v, 4);
        v += __shfl_xor(v, 8);
        if (fl == 0)
          atomicAdd(&rsum[rowg0 + mi * 16 + (quad << 2) + r], v);
      }
  } else {
    float* Co = Oall + (size_t)bz * 2 * CH * NN;     // first CV block
    const float* rsum = rsum_all + (size_t)bz * NN;
    float* scr = (float*)AsB + wv * 1024;            // 16x64 f32 per wave

    float inv[4];
#pragma unroll
    for (int nj = 0; nj < 4; ++nj) inv[nj] = 1.f / rsum[colbase + nj * 16 + fl];

#pragma unroll
    for (int mi = 0; mi < 8; ++mi) {
#pragma unroll
      for (int nj = 0; nj < 4; ++nj)
#pragma unroll
        for (int r = 0; r < 4; ++r) {
          int row = (quad << 2) + r;
          int chunk = (nj * 4 + (fl >> 2)) ^ (row & 15);
          scr[row * 64 + chunk * 4 + (fl & 3)] = acc[mi][nj][r] * inv[nj];
        }
      LDS_FENCE();
#pragma unroll
      for (int p = 0; p < 4; ++p) {
        int row = (p << 2) + (lane >> 4);
        int c = lane & 15;
        int chunk = c ^ (row & 15);
        f32x4 v = *(const f32x4*)(scr + row * 64 + chunk * 4);
        *(f32x4*)(Co + (size_t)(rowg0 + mi * 16 + row) * NN + colbase + c * 4) = v;
      }
      MEM_FENCE();
    }
  }
}

// ---------------------------------------------------------------------------
extern "C" void kernel_launch(void* const* d_in, const int* in_sizes, int n_in,
                              void* d_out, int out_size, void* d_ws, size_t ws_size,
                              hipStream_t stream) {
  const float* prev_key   = (const float*)d_in[0];
  const float* prev_value = (const float*)d_in[1];
  const float* curr_key   = (const float*)d_in[2];
  const float* curr_value = (const float*)d_in[3];
  float* out = (float*)d_out;

  char* ws = (char*)d_ws;
  bf16* P     = (bf16*)(ws);                        // 256 MB [B][N][N]
  bf16* mk_t  = (bf16*)(ws + 268435456u);           //  64 MB [B][N][C]
  bf16* qk_t  = (bf16*)(ws + 335544320u);           //  64 MB [B][N][C]
  bf16* mo_b  = (bf16*)(ws + 402653184u);           //  64 MB [B][C][N]
  float* a_sq = (float*)(ws + 469762048u);          // 128 KB [B][N]
  float* rsum = a_sq + (size_t)BATCH * NN;          // 128 KB [B][N]

  hipMemsetAsync(a_sq, 0, 2ull * BATCH * NN * sizeof(float), stream);

  transpose_cast_v<true><<<dim3(NN / 64, CH / 64, BATCH), 256, 0, stream>>>(
      prev_key, mk_t, a_sq);
  transpose_cast_v<false><<<dim3(NN / 64, CH / 64, BATCH), 256, 0, stream>>>(
      curr_key, qk_t, nullptr);

  // GEMM1 (fused): 4096 gemm blocks + 1024 interleaved memory-task blocks
  // (convert prev_value -> mo_b for GEMM2; copy curr_value -> out 2nd half).
  gemm_s3<CH, 0, 16, 32, true><<<dim3(5120), dim3(256), 0, stream>>>(
      qk_t, mk_t, P, nullptr, a_sq, rsum,
      (const float4*)prev_value, (bhalf4*)mo_b,
      (const float4*)curr_value, (float4*)out);

  // GEMM2: mem = mo * P^T  (M=1024, N=4096, K=4096).
  gemm_s3<NN, 1, 4, 32, false><<<dim3(4 * 32 * BATCH), dim3(256), 0, stream>>>(
      mo_b, P, nullptr, out, nullptr, rsum,
      nullptr, nullptr, nullptr, nullptr);
}